// Round 3
// baseline (854.192 us; speedup 1.0000x reference)
//
#include <hip/hip_runtime.h>

#define D 128
#define HEADS 8
#define CH 16
#define NEG 0.2f
#define LNEPS 1e-5f
#define ZPAD 136   // LDS row stride in bf16 elems (272B, 16B-aligned)
#define EB 64      // edges per block in edge_kernel

typedef __attribute__((ext_vector_type(8))) short bf16x8;
typedef __attribute__((ext_vector_type(4))) float f32x4;

#define MFMA(a, b, c) __builtin_amdgcn_mfma_f32_16x16x32_bf16(a, b, c, 0, 0, 0)

__device__ __forceinline__ short f2bf(float f) {
    unsigned u = __builtin_bit_cast(unsigned, f);
    unsigned r = (u + 0x7fffu + ((u >> 16) & 1u)) >> 16;
    return (short)r;
}
__device__ __forceinline__ float bf2f(unsigned short us) {
    unsigned u = ((unsigned)us) << 16;
    return __builtin_bit_cast(float, u);
}
__device__ __forceinline__ bf16x8 pack8(f32x4 lo, f32x4 hi) {
    bf16x8 r;
    r[0] = f2bf(lo[0]); r[1] = f2bf(lo[1]); r[2] = f2bf(lo[2]); r[3] = f2bf(lo[3]);
    r[4] = f2bf(hi[0]); r[5] = f2bf(hi[1]); r[6] = f2bf(hi[2]); r[7] = f2bf(hi[3]);
    return r;
}

// ---- K0: convert all weight matrices to bf16 ----
__global__ void convert_weights(const float* __restrict__ wl, const float* __restrict__ wr,
                                const float* __restrict__ we, const float* __restrict__ fc,
                                const float* __restrict__ pj, short* __restrict__ out) {
    int idx = blockIdx.x * 256 + threadIdx.x;
    float v;
    if (idx < 16384) v = wl[idx];
    else if (idx < 32768) v = wr[idx - 16384];
    else if (idx < 49152) v = we[idx - 32768];
    else if (idx < 114688) v = fc[idx - 49152];
    else if (idx < 180224) v = pj[idx - 114688];
    else return;
    out[idx] = f2bf(v);
}

// ---- K1: LayerNorm1 -> bf16 ----
__global__ void ln_kernel(const float* __restrict__ x, const float* __restrict__ w,
                          short* __restrict__ h, int n) {
    int row = blockIdx.x * 4 + (threadIdx.x >> 6);
    if (row >= n) return;
    int l = threadIdx.x & 63;
    long base = (long)row * D;
    float a = x[base + l], b = x[base + l + 64];
    float s = a + b, ss = a * a + b * b;
    #pragma unroll
    for (int m = 1; m < 64; m <<= 1) { s += __shfl_xor(s, m); ss += __shfl_xor(ss, m); }
    float mu = s * (1.0f / 128.0f);
    float var = ss * (1.0f / 128.0f) - mu * mu;
    float rstd = rsqrtf(var + LNEPS);
    h[base + l]      = f2bf((a - mu) * rstd * w[l]);
    h[base + l + 64] = f2bf((b - mu) * rstd * w[l + 64]);
}

// ---- K2: xl = h@Wl^T + bl ; xr = h@Wr^T + br  -> bf16 outputs ----
__global__ __launch_bounds__(256) void node_lin_kernel(
        const short* __restrict__ h, const short* __restrict__ wl, const short* __restrict__ wr,
        const float* __restrict__ bl, const float* __restrict__ br,
        short* __restrict__ xl, short* __restrict__ xr, int n) {
    int wave = threadIdx.x >> 6, l = threadIdx.x & 63;
    int rbase = blockIdx.x * 64 + wave * 16;
    int g = l >> 4, c = l & 15;
    f32x4 acc[16];
    #pragma unroll
    for (int t = 0; t < 16; t++) acc[t] = (f32x4){0.f, 0.f, 0.f, 0.f};
    int arow = rbase + c;
    #pragma unroll
    for (int kk = 0; kk < 4; kk++) {
        int k0 = kk * 32 + g * 8;
        bf16x8 af = {};
        if (arow < n) af = *(const bf16x8*)(h + (long)arow * D + k0);
        #pragma unroll
        for (int t = 0; t < 16; t++) {
            const short* w = (t < 8) ? wl : wr;
            int col = (t & 7) * 16 + c;
            bf16x8 bf = *(const bf16x8*)(w + col * D + k0);
            acc[t] = MFMA(af, bf, acc[t]);
        }
    }
    #pragma unroll
    for (int t = 0; t < 16; t++) {
        int col = (t & 7) * 16 + c;
        short* out = (t < 8) ? xl : xr;
        float bias = (t < 8) ? bl[col] : br[col];
        #pragma unroll
        for (int r = 0; r < 4; r++) {
            int row = rbase + g * 4 + r;
            if (row < n) out[(long)row * D + col] = f2bf(acc[t][r] + bias);
        }
    }
}

// ---- CSR build: histogram / 3-phase multi-block scan / place ----
__global__ void hist_kernel(const int* __restrict__ dst, int* __restrict__ counts, int nE) {
    int e = blockIdx.x * 256 + threadIdx.x;
    if (e < nE) atomicAdd(&counts[dst[e]], 1);
}

// per-block (1024 elems) exclusive scan; block total -> blocksum
__global__ void scan1_kernel(const int* __restrict__ counts, int* __restrict__ offsets,
                             int* __restrict__ blocksum, int n) {
    __shared__ int sd[1024];
    int tid = threadIdx.x;
    int gid = blockIdx.x * 1024 + tid;
    int v = (gid < n) ? counts[gid] : 0;
    sd[tid] = v;
    __syncthreads();
    int acc = v;
    #pragma unroll
    for (int off = 1; off < 1024; off <<= 1) {
        int t = (tid >= off) ? sd[tid - off] : 0;
        __syncthreads();
        acc += t;
        sd[tid] = acc;
        __syncthreads();
    }
    if (gid < n) offsets[gid] = acc - v;
    if (tid == 1023) blocksum[blockIdx.x] = acc;
}

// single block: exclusive scan of nb block sums (nb <= 256)
__global__ void scan2_kernel(int* __restrict__ blocksum, int nb) {
    __shared__ int sd[256];
    int tid = threadIdx.x;
    int v = (tid < nb) ? blocksum[tid] : 0;
    sd[tid] = v;
    __syncthreads();
    int acc = v;
    #pragma unroll
    for (int off = 1; off < 256; off <<= 1) {
        int t = (tid >= off) ? sd[tid - off] : 0;
        __syncthreads();
        acc += t;
        sd[tid] = acc;
        __syncthreads();
    }
    if (tid < nb) blocksum[tid] = acc - v;
}

// add block bases; also init cursor
__global__ void scan3_kernel(int* __restrict__ offsets, const int* __restrict__ blocksum,
                             int* __restrict__ cursor, int n) {
    int gid = blockIdx.x * 256 + threadIdx.x;
    if (gid < n) {
        int o = offsets[gid] + blocksum[gid >> 10];
        offsets[gid] = o;
        cursor[gid] = o;
    }
}

__global__ void place_kernel(const int* __restrict__ dst, int* __restrict__ cursor,
                             int* __restrict__ eid, int nE) {
    int e = blockIdx.x * 256 + threadIdx.x;
    if (e < nE) {
        int pos = atomicAdd(&cursor[dst[e]], 1);
        eid[pos] = e;
    }
}

// ---- K3: fused edge GEMM + leaky + att-dot + exp -> num (no atomics) ----
// 256 thr = 4 waves, EB=64 edges/block (16 per wave). Small LDS -> 8 blocks/CU.
__global__ __launch_bounds__(256, 8) void edge_kernel(
        const float* __restrict__ ea, const short* __restrict__ we,
        const int* __restrict__ src, const int* __restrict__ dst,
        const short* __restrict__ xl, const short* __restrict__ xr,
        const float* __restrict__ att, float* __restrict__ num, int nE) {
    __shared__ short zsum[EB * ZPAD];   // 17408 B
    int tid = threadIdx.x;
    int wave = tid >> 6, l = tid & 63;
    int g = l >> 4, c = l & 15;
    long blkbase = (long)blockIdx.x * EB;

    // phase 1: cooperative gather + presum (thread: chunk=tid&15, edges (tid>>4)+16i)
    int chunk = tid & 15;
    int er0 = tid >> 4;
    #pragma unroll
    for (int i = 0; i < EB / 16; i++) {
        int el = er0 + 16 * i;
        long e = blkbase + el;
        long ec = (e < nE) ? e : 0;
        int s = src[ec], d = dst[ec];
        bf16x8 a = *(const bf16x8*)(xl + (long)s * D + chunk * 8);
        bf16x8 b = *(const bf16x8*)(xr + (long)d * D + chunk * 8);
        bf16x8 r;
        #pragma unroll
        for (int j = 0; j < 8; j++) r[j] = f2bf(bf2f((unsigned short)a[j]) + bf2f((unsigned short)b[j]));
        *(bf16x8*)(zsum + el * ZPAD + chunk * 8) = r;
    }

    // phase 2: MFMA e = ea @ we^T (this wave's 16 edges)
    f32x4 acc[8];
    #pragma unroll
    for (int t = 0; t < 8; t++) acc[t] = (f32x4){0.f, 0.f, 0.f, 0.f};
    long ebase = blkbase + wave * 16;
    #pragma unroll
    for (int kk = 0; kk < 4; kk++) {
        int k0 = kk * 32 + g * 8;
        long erow = ebase + c;
        bf16x8 af = (bf16x8){};
        if (erow < nE) {
            const float* p = ea + erow * D + k0;
            af = pack8(*(const f32x4*)p, *(const f32x4*)(p + 4));
        }
        #pragma unroll
        for (int t = 0; t < 8; t++) {
            bf16x8 bf = *(const bf16x8*)(we + (t * CH + c) * D + k0);
            acc[t] = MFMA(af, bf, acc[t]);
        }
    }
    __syncthreads();

    // phase 3: z = leaky(e + zsum); logit = sum_c z*att; num = exp(logit)
    #pragma unroll
    for (int t = 0; t < 8; t++) {
        float av = att[t * CH + c];
        float part[4];
        #pragma unroll
        for (int r = 0; r < 4; r++) {
            int el = wave * 16 + g * 4 + r;
            float v = acc[t][r] + bf2f((unsigned short)zsum[el * ZPAD + t * CH + c]);
            v = v > 0.f ? v : NEG * v;
            part[r] = v * av;
        }
        #pragma unroll
        for (int m = 1; m < 16; m <<= 1) {
            #pragma unroll
            for (int r = 0; r < 4; r++) part[r] += __shfl_xor(part[r], m);
        }
        if (c == 0) {
            #pragma unroll
            for (int r = 0; r < 4; r++) {
                long e = ebase + g * 4 + r;
                if (e < nE) num[e * HEADS + t] = expf(part[r]);
            }
        }
    }
}

// ---- K4: per-node aggregation (no atomics) + residual + bias + LN2 fused ----
__global__ __launch_bounds__(256) void aggregate_kernel(
        const int* __restrict__ src, const int* __restrict__ eid,
        const int* __restrict__ offsets, const int* __restrict__ counts,
        const float* __restrict__ num, const short* __restrict__ xl,
        const float* __restrict__ x, const float* __restrict__ ab,
        const float* __restrict__ w2, float* __restrict__ x_mid,
        short* __restrict__ h2, int n) {
    int node = blockIdx.x * 4 + (threadIdx.x >> 6);
    if (node >= n) return;
    int l = threadIdx.x & 63;
    int h = l >> 3;                 // head of cols 2l, 2l+1
    int start = offsets[node], cnt = counts[node];
    float den = 0.f;
    for (int i = 0; i < cnt; i++) den += num[(long)eid[start + i] * HEADS + h];
    float rden = cnt > 0 ? 1.f / den : 0.f;
    float a0 = 0.f, a1 = 0.f;
    for (int i = 0; i < cnt; i++) {
        int e = eid[start + i];
        float al = num[(long)e * HEADS + h] * rden;
        int s = src[e];
        unsigned u = *(const unsigned*)(xl + (long)s * D + 2 * l);
        a0 += bf2f((unsigned short)(u & 0xffffu)) * al;
        a1 += bf2f((unsigned short)(u >> 16)) * al;
    }
    long base = (long)node * D;
    float2 xv = *(const float2*)(x + base + 2 * l);
    float2 abv = *(const float2*)(ab + 2 * l);
    float xm0 = xv.x + a0 + abv.x;
    float xm1 = xv.y + a1 + abv.y;
    *(float2*)(x_mid + base + 2 * l) = make_float2(xm0, xm1);
    float s_ = xm0 + xm1, ss = xm0 * xm0 + xm1 * xm1;
    #pragma unroll
    for (int m = 1; m < 64; m <<= 1) { s_ += __shfl_xor(s_, m); ss += __shfl_xor(ss, m); }
    float mu = s_ * (1.0f / 128.0f);
    float var = ss * (1.0f / 128.0f) - mu * mu;
    float rstd = rsqrtf(var + LNEPS);
    float2 wv = *(const float2*)(w2 + 2 * l);
    h2[base + 2 * l]     = f2bf((xm0 - mu) * rstd * wv.x);
    h2[base + 2 * l + 1] = f2bf((xm1 - mu) * rstd * wv.y);
}

// ---- K6: t = relu(h2 @ fc_w^T) -> bf16 [N,512] ----
__global__ __launch_bounds__(256) void fc_kernel(const short* __restrict__ h2,
                                                 const short* __restrict__ wfc,
                                                 short* __restrict__ t512, int n) {
    int wave = threadIdx.x >> 6, l = threadIdx.x & 63;
    int rbase = blockIdx.x * 64 + wave * 16;
    int cbase = blockIdx.y * 256;
    int g = l >> 4, c = l & 15;
    f32x4 acc[16];
    #pragma unroll
    for (int t = 0; t < 16; t++) acc[t] = (f32x4){0.f, 0.f, 0.f, 0.f};
    int arow = rbase + c;
    #pragma unroll
    for (int kk = 0; kk < 4; kk++) {
        int k0 = kk * 32 + g * 8;
        bf16x8 af = {};
        if (arow < n) af = *(const bf16x8*)(h2 + (long)arow * D + k0);
        #pragma unroll
        for (int t = 0; t < 16; t++) {
            int col = cbase + t * 16 + c;
            bf16x8 bf = *(const bf16x8*)(wfc + (long)col * D + k0);
            acc[t] = MFMA(af, bf, acc[t]);
        }
    }
    #pragma unroll
    for (int t = 0; t < 16; t++) {
        int col = cbase + t * 16 + c;
        #pragma unroll
        for (int r = 0; r < 4; r++) {
            int row = rbase + g * 4 + r;
            if (row < n) {
                float v = acc[t][r];
                t512[(long)row * 512 + col] = f2bf(v > 0.f ? v : 0.f);
            }
        }
    }
}

// ---- K7: out = x_mid + t @ proj_w^T ----
__global__ __launch_bounds__(256) void proj_kernel(const short* __restrict__ t512,
                                                   const short* __restrict__ wpj,
                                                   const float* __restrict__ x_mid,
                                                   float* __restrict__ out, int n) {
    int wave = threadIdx.x >> 6, l = threadIdx.x & 63;
    int rbase = blockIdx.x * 64 + wave * 16;
    int g = l >> 4, c = l & 15;
    f32x4 acc[8];
    #pragma unroll
    for (int t = 0; t < 8; t++) acc[t] = (f32x4){0.f, 0.f, 0.f, 0.f};
    int arow = rbase + c;
    #pragma unroll
    for (int kk = 0; kk < 16; kk++) {
        int k0 = kk * 32 + g * 8;
        bf16x8 af = {};
        if (arow < n) af = *(const bf16x8*)(t512 + (long)arow * 512 + k0);
        #pragma unroll
        for (int t = 0; t < 8; t++) {
            bf16x8 bf = *(const bf16x8*)(wpj + (long)(t * 16 + c) * 512 + k0);
            acc[t] = MFMA(af, bf, acc[t]);
        }
    }
    #pragma unroll
    for (int t = 0; t < 8; t++) {
        int col = t * 16 + c;
        #pragma unroll
        for (int r = 0; r < 4; r++) {
            int row = rbase + g * 4 + r;
            if (row < n) out[(long)row * D + col] = x_mid[(long)row * D + col] + acc[t][r];
        }
    }
}

extern "C" void kernel_launch(void* const* d_in, const int* in_sizes, int n_in,
                              void* d_out, int out_size, void* d_ws, size_t ws_size,
                              hipStream_t stream) {
    const float* x    = (const float*)d_in[0];
    const int*   eidx = (const int*)d_in[1];
    const float* ea   = (const float*)d_in[2];
    const float* ln1w = (const float*)d_in[3];
    const float* wl   = (const float*)d_in[4];
    const float* bl   = (const float*)d_in[5];
    const float* wr   = (const float*)d_in[6];
    const float* br   = (const float*)d_in[7];
    const float* we   = (const float*)d_in[8];
    const float* att  = (const float*)d_in[9];
    const float* ab   = (const float*)d_in[10];
    const float* ln2w = (const float*)d_in[11];
    const float* wfc  = (const float*)d_in[12];
    const float* wpj  = (const float*)d_in[13];
    int N = in_sizes[0] / D;
    int E = in_sizes[1] / 2;
    const int* srcp = eidx;
    const int* dstp = eidx + E;

    char* ws = (char*)d_ws;
    size_t NB2 = (size_t)N * D * 2;       // bf16 node matrix
    size_t NB4 = (size_t)N * D * 4;       // fp32 node matrix
    size_t E84 = (size_t)E * HEADS * 4;   // num
    size_t o = 0;
    short* xl_bf = (short*)(ws + o); o += NB2;
    short* xr_bf = (short*)(ws + o); o += NB2;
    float* num   = (float*)(ws + o); o += E84;
    float* xmid  = (float*)(ws + o); o += NB4;
    short* hbuf  = (short*)(ws + o); o += NB2;
    short* wbf   = (short*)(ws + o); o += 180224 * 2;
    int* counts  = (int*)(ws + o);   o += (size_t)N * 4;
    int* offsets = (int*)(ws + o);   o += (size_t)N * 4;
    int* cursor  = (int*)(ws + o);   o += (size_t)N * 4;
    int* eid     = (int*)(ws + o);   o += (size_t)E * 4;
    int* blocksum= (int*)(ws + o);   o += 256 * 4;
    short* t512  = (short*)ws;  // overlays xl_bf+xr_bf+num after aggregate (N*512*2)

    int nb = (N + 1023) / 1024;

    hipMemsetAsync(counts, 0, (size_t)N * 4, stream);

    convert_weights<<<704, 256, 0, stream>>>(wl, wr, we, wfc, wpj, wbf);
    ln_kernel<<<(N + 3) / 4, 256, 0, stream>>>(x, ln1w, hbuf, N);
    node_lin_kernel<<<(N + 63) / 64, 256, 0, stream>>>(hbuf, wbf, wbf + 16384,
                                                       bl, br, xl_bf, xr_bf, N);
    hist_kernel<<<(E + 255) / 256, 256, 0, stream>>>(dstp, counts, E);
    scan1_kernel<<<nb, 1024, 0, stream>>>(counts, offsets, blocksum, N);
    scan2_kernel<<<1, 256, 0, stream>>>(blocksum, nb);
    scan3_kernel<<<(N + 255) / 256, 256, 0, stream>>>(offsets, blocksum, cursor, N);
    place_kernel<<<(E + 255) / 256, 256, 0, stream>>>(dstp, cursor, eid, E);
    edge_kernel<<<(E + EB - 1) / EB, 256, 0, stream>>>(ea, wbf + 32768, srcp, dstp,
                                                       xl_bf, xr_bf, att, num, E);
    aggregate_kernel<<<(N + 3) / 4, 256, 0, stream>>>(srcp, eid, offsets, counts,
                                                      num, xl_bf, x, ab, ln2w,
                                                      xmid, hbuf, N);
    fc_kernel<<<dim3((N + 63) / 64, 2), 256, 0, stream>>>(hbuf, wbf + 49152, t512, N);
    proj_kernel<<<(N + 63) / 64, 256, 0, stream>>>(t512, wbf + 114688, xmid,
                                                   (float*)d_out, N);
}

// Round 4
// 735.361 us; speedup vs baseline: 1.1616x; 1.1616x over previous
//
#include <hip/hip_runtime.h>

#define D 128
#define HEADS 8
#define CH 16
#define NEG 0.2f
#define LNEPS 1e-5f

typedef __attribute__((ext_vector_type(8))) short bf16x8;
typedef __attribute__((ext_vector_type(4))) float f32x4;

#define MFMA(a, b, c) __builtin_amdgcn_mfma_f32_16x16x32_bf16(a, b, c, 0, 0, 0)

__device__ __forceinline__ short f2bf(float f) {
    unsigned u = __builtin_bit_cast(unsigned, f);
    unsigned r = (u + 0x7fffu + ((u >> 16) & 1u)) >> 16;
    return (short)r;
}
__device__ __forceinline__ float bflo(unsigned u) {
    return __builtin_bit_cast(float, u << 16);
}
__device__ __forceinline__ float bfhi(unsigned u) {
    return __builtin_bit_cast(float, u & 0xffff0000u);
}
__device__ __forceinline__ bf16x8 pack8(f32x4 lo, f32x4 hi) {
    bf16x8 r;
    r[0] = f2bf(lo[0]); r[1] = f2bf(lo[1]); r[2] = f2bf(lo[2]); r[3] = f2bf(lo[3]);
    r[4] = f2bf(hi[0]); r[5] = f2bf(hi[1]); r[6] = f2bf(hi[2]); r[7] = f2bf(hi[3]);
    return r;
}

// ---- K0: convert all weight matrices to bf16 ----
__global__ void convert_weights(const float* __restrict__ wl, const float* __restrict__ wr,
                                const float* __restrict__ we, const float* __restrict__ fc,
                                const float* __restrict__ pj, short* __restrict__ out) {
    int idx = blockIdx.x * 256 + threadIdx.x;
    float v;
    if (idx < 16384) v = wl[idx];
    else if (idx < 32768) v = wr[idx - 16384];
    else if (idx < 49152) v = we[idx - 32768];
    else if (idx < 114688) v = fc[idx - 49152];
    else if (idx < 180224) v = pj[idx - 114688];
    else return;
    out[idx] = f2bf(v);
}

// ---- K1: LayerNorm1 -> bf16 ----
__global__ void ln_kernel(const float* __restrict__ x, const float* __restrict__ w,
                          short* __restrict__ h, int n) {
    int row = blockIdx.x * 4 + (threadIdx.x >> 6);
    if (row >= n) return;
    int l = threadIdx.x & 63;
    long base = (long)row * D;
    float a = x[base + l], b = x[base + l + 64];
    float s = a + b, ss = a * a + b * b;
    #pragma unroll
    for (int m = 1; m < 64; m <<= 1) { s += __shfl_xor(s, m); ss += __shfl_xor(ss, m); }
    float mu = s * (1.0f / 128.0f);
    float var = ss * (1.0f / 128.0f) - mu * mu;
    float rstd = rsqrtf(var + LNEPS);
    h[base + l]      = f2bf((a - mu) * rstd * w[l]);
    h[base + l + 64] = f2bf((b - mu) * rstd * w[l + 64]);
}

// ---- K2: xl = h@Wl^T + bl ; xr = h@Wr^T + br  -> bf16 outputs ----
__global__ __launch_bounds__(256) void node_lin_kernel(
        const short* __restrict__ h, const short* __restrict__ wl, const short* __restrict__ wr,
        const float* __restrict__ bl, const float* __restrict__ br,
        short* __restrict__ xl, short* __restrict__ xr, int n) {
    int wave = threadIdx.x >> 6, l = threadIdx.x & 63;
    int rbase = blockIdx.x * 64 + wave * 16;
    int g = l >> 4, c = l & 15;
    f32x4 acc[16];
    #pragma unroll
    for (int t = 0; t < 16; t++) acc[t] = (f32x4){0.f, 0.f, 0.f, 0.f};
    int arow = rbase + c;
    #pragma unroll
    for (int kk = 0; kk < 4; kk++) {
        int k0 = kk * 32 + g * 8;
        bf16x8 af = {};
        if (arow < n) af = *(const bf16x8*)(h + (long)arow * D + k0);
        #pragma unroll
        for (int t = 0; t < 16; t++) {
            const short* w = (t < 8) ? wl : wr;
            int col = (t & 7) * 16 + c;
            bf16x8 bf = *(const bf16x8*)(w + col * D + k0);
            acc[t] = MFMA(af, bf, acc[t]);
        }
    }
    #pragma unroll
    for (int t = 0; t < 16; t++) {
        int col = (t & 7) * 16 + c;
        short* out = (t < 8) ? xl : xr;
        float bias = (t < 8) ? bl[col] : br[col];
        #pragma unroll
        for (int r = 0; r < 4; r++) {
            int row = rbase + g * 4 + r;
            if (row < n) out[(long)row * D + col] = f2bf(acc[t][r] + bias);
        }
    }
}

// ---- CSR build: histogram / 3-phase multi-block scan / place ----
__global__ void hist_kernel(const int* __restrict__ dst, int* __restrict__ counts, int nE) {
    int e = blockIdx.x * 256 + threadIdx.x;
    if (e < nE) atomicAdd(&counts[dst[e]], 1);
}

__global__ void scan1_kernel(const int* __restrict__ counts, int* __restrict__ offsets,
                             int* __restrict__ blocksum, int n) {
    __shared__ int sd[1024];
    int tid = threadIdx.x;
    int gid = blockIdx.x * 1024 + tid;
    int v = (gid < n) ? counts[gid] : 0;
    sd[tid] = v;
    __syncthreads();
    int acc = v;
    #pragma unroll
    for (int off = 1; off < 1024; off <<= 1) {
        int t = (tid >= off) ? sd[tid - off] : 0;
        __syncthreads();
        acc += t;
        sd[tid] = acc;
        __syncthreads();
    }
    if (gid < n) offsets[gid] = acc - v;
    if (tid == 1023) blocksum[blockIdx.x] = acc;
}

__global__ void scan2_kernel(int* __restrict__ blocksum, int nb) {
    __shared__ int sd[256];
    int tid = threadIdx.x;
    int v = (tid < nb) ? blocksum[tid] : 0;
    sd[tid] = v;
    __syncthreads();
    int acc = v;
    #pragma unroll
    for (int off = 1; off < 256; off <<= 1) {
        int t = (tid >= off) ? sd[tid - off] : 0;
        __syncthreads();
        acc += t;
        sd[tid] = acc;
        __syncthreads();
    }
    if (tid < nb) blocksum[tid] = acc - v;
}

__global__ void scan3_kernel(int* __restrict__ offsets, const int* __restrict__ blocksum,
                             int* __restrict__ cursor, int n) {
    int gid = blockIdx.x * 256 + threadIdx.x;
    if (gid < n) {
        int o = offsets[gid] + blocksum[gid >> 10];
        offsets[gid] = o;
        cursor[gid] = o;
    }
}

// place: assign CSR slot; emit posOf (edge->slot) and src_perm (slot->src)
__global__ void place_kernel(const int* __restrict__ src, const int* __restrict__ dst,
                             int* __restrict__ cursor, int* __restrict__ posOf,
                             int* __restrict__ src_perm, int nE) {
    int e = blockIdx.x * 256 + threadIdx.x;
    if (e < nE) {
        int pos = atomicAdd(&cursor[dst[e]], 1);
        posOf[e] = pos;
        src_perm[pos] = src[e];
    }
}

// ---- K3: fused edge GEMM (swapped operands) + leaky + att-dot + exp -> num_perm ----
// 256 thr = 4 waves; each wave owns 16 edges; lane l: edge el=(l&15), chan group g=(l>>4).
// No LDS, no syncthreads: C[channel][edge] layout makes gathers & reduce lane-local.
__global__ __launch_bounds__(256) void edge_kernel(
        const float* __restrict__ ea, const short* __restrict__ we,
        const int* __restrict__ src, const int* __restrict__ dst,
        const int* __restrict__ posOf,
        const short* __restrict__ xl, const short* __restrict__ xr,
        const float* __restrict__ att, float* __restrict__ num_perm, int nE) {
    int tid = threadIdx.x;
    int wave = tid >> 6, l = tid & 63;
    int el = l & 15, g = l >> 4;
    long e = (long)blockIdx.x * 64 + wave * 16 + el;
    long ec = (e < nE) ? e : (nE - 1);
    int s = src[ec], d = dst[ec];

    // issue all gathers early: 8B per head-tile from xl[src] and xr[dst]
    uint2 gl[8], gr[8];
    #pragma unroll
    for (int t = 0; t < 8; t++) {
        gl[t] = *(const uint2*)(xl + (long)s * D + t * CH + g * 4);
        gr[t] = *(const uint2*)(xr + (long)d * D + t * CH + g * 4);
    }

    // swapped MFMA: acc[t] holds C[chan t*16+g*4+r][edge el]
    f32x4 acc[8];
    #pragma unroll
    for (int t = 0; t < 8; t++) acc[t] = (f32x4){0.f, 0.f, 0.f, 0.f};
    #pragma unroll
    for (int kk = 0; kk < 4; kk++) {
        int k0 = kk * 32 + g * 8;
        const float* p = ea + ec * D + k0;
        bf16x8 bfrag = pack8(*(const f32x4*)p, *(const f32x4*)(p + 4));
        #pragma unroll
        for (int t = 0; t < 8; t++) {
            bf16x8 afrag = *(const bf16x8*)(we + (t * CH + el) * D + k0);
            acc[t] = MFMA(afrag, bfrag, acc[t]);
        }
    }

    // epilogue: z = leaky(e + xl + xr); per-head dot with att; reduce over g-groups
    float logit[8];
    #pragma unroll
    for (int t = 0; t < 8; t++) {
        f32x4 av = *(const f32x4*)(att + t * CH + g * 4);
        float zl0 = bflo(gl[t].x), zl1 = bfhi(gl[t].x), zl2 = bflo(gl[t].y), zl3 = bfhi(gl[t].y);
        float zr0 = bflo(gr[t].x), zr1 = bfhi(gr[t].x), zr2 = bflo(gr[t].y), zr3 = bfhi(gr[t].y);
        float v0 = acc[t][0] + zl0 + zr0;
        float v1 = acc[t][1] + zl1 + zr1;
        float v2 = acc[t][2] + zl2 + zr2;
        float v3 = acc[t][3] + zl3 + zr3;
        v0 = v0 > 0.f ? v0 : NEG * v0;
        v1 = v1 > 0.f ? v1 : NEG * v1;
        v2 = v2 > 0.f ? v2 : NEG * v2;
        v3 = v3 > 0.f ? v3 : NEG * v3;
        float lg = v0 * av[0];
        lg = fmaf(v1, av[1], lg);
        lg = fmaf(v2, av[2], lg);
        lg = fmaf(v3, av[3], lg);
        lg += __shfl_xor(lg, 16);
        lg += __shfl_xor(lg, 32);
        logit[t] = lg;
    }
    if (g == 0 && e < nE) {
        int pos = posOf[e];
        float4 o0 = make_float4(__expf(logit[0]), __expf(logit[1]),
                                __expf(logit[2]), __expf(logit[3]));
        float4 o1 = make_float4(__expf(logit[4]), __expf(logit[5]),
                                __expf(logit[6]), __expf(logit[7]));
        *(float4*)(num_perm + (long)pos * HEADS) = o0;
        *(float4*)(num_perm + (long)pos * HEADS + 4) = o1;
    }
}

// ---- K4: per-node aggregation (contiguous CSR reads) + residual + bias + LN2 ----
__global__ __launch_bounds__(256) void aggregate_kernel(
        const int* __restrict__ src_perm, const int* __restrict__ offsets,
        const int* __restrict__ counts, const float* __restrict__ num_perm,
        const short* __restrict__ xl, const float* __restrict__ x,
        const float* __restrict__ ab, const float* __restrict__ w2,
        float* __restrict__ x_mid, short* __restrict__ h2, int n) {
    int node = blockIdx.x * 4 + (threadIdx.x >> 6);
    if (node >= n) return;
    int l = threadIdx.x & 63;
    int h = l >> 3;                 // head of cols 2l, 2l+1
    int start = offsets[node], cnt = counts[node];
    float a0 = 0.f, a1 = 0.f, den = 0.f;
    for (int i = 0; i < cnt; i++) {
        float nm = num_perm[(long)(start + i) * HEADS + h];
        int s = src_perm[start + i];
        unsigned u = *(const unsigned*)(xl + (long)s * D + 2 * l);
        a0 = fmaf(bflo(u), nm, a0);
        a1 = fmaf(bfhi(u), nm, a1);
        den += nm;
    }
    float rden = cnt > 0 ? 1.f / den : 0.f;
    a0 *= rden; a1 *= rden;
    long base = (long)node * D;
    float2 xv = *(const float2*)(x + base + 2 * l);
    float2 abv = *(const float2*)(ab + 2 * l);
    float xm0 = xv.x + a0 + abv.x;
    float xm1 = xv.y + a1 + abv.y;
    *(float2*)(x_mid + base + 2 * l) = make_float2(xm0, xm1);
    float s_ = xm0 + xm1, ss = xm0 * xm0 + xm1 * xm1;
    #pragma unroll
    for (int m = 1; m < 64; m <<= 1) { s_ += __shfl_xor(s_, m); ss += __shfl_xor(ss, m); }
    float mu = s_ * (1.0f / 128.0f);
    float var = ss * (1.0f / 128.0f) - mu * mu;
    float rstd = rsqrtf(var + LNEPS);
    float2 wv = *(const float2*)(w2 + 2 * l);
    h2[base + 2 * l]     = f2bf((xm0 - mu) * rstd * wv.x);
    h2[base + 2 * l + 1] = f2bf((xm1 - mu) * rstd * wv.y);
}

// ---- K6: t = relu(h2 @ fc_w^T) -> bf16 [N,512] ----
__global__ __launch_bounds__(256) void fc_kernel(const short* __restrict__ h2,
                                                 const short* __restrict__ wfc,
                                                 short* __restrict__ t512, int n) {
    int wave = threadIdx.x >> 6, l = threadIdx.x & 63;
    int rbase = blockIdx.x * 64 + wave * 16;
    int cbase = blockIdx.y * 256;
    int g = l >> 4, c = l & 15;
    f32x4 acc[16];
    #pragma unroll
    for (int t = 0; t < 16; t++) acc[t] = (f32x4){0.f, 0.f, 0.f, 0.f};
    int arow = rbase + c;
    #pragma unroll
    for (int kk = 0; kk < 4; kk++) {
        int k0 = kk * 32 + g * 8;
        bf16x8 af = {};
        if (arow < n) af = *(const bf16x8*)(h2 + (long)arow * D + k0);
        #pragma unroll
        for (int t = 0; t < 16; t++) {
            int col = cbase + t * 16 + c;
            bf16x8 bf = *(const bf16x8*)(wfc + (long)col * D + k0);
            acc[t] = MFMA(af, bf, acc[t]);
        }
    }
    #pragma unroll
    for (int t = 0; t < 16; t++) {
        int col = cbase + t * 16 + c;
        #pragma unroll
        for (int r = 0; r < 4; r++) {
            int row = rbase + g * 4 + r;
            if (row < n) {
                float v = acc[t][r];
                t512[(long)row * 512 + col] = f2bf(v > 0.f ? v : 0.f);
            }
        }
    }
}

// ---- K7: out = x_mid + t @ proj_w^T ----
__global__ __launch_bounds__(256) void proj_kernel(const short* __restrict__ t512,
                                                   const short* __restrict__ wpj,
                                                   const float* __restrict__ x_mid,
                                                   float* __restrict__ out, int n) {
    int wave = threadIdx.x >> 6, l = threadIdx.x & 63;
    int rbase = blockIdx.x * 64 + wave * 16;
    int g = l >> 4, c = l & 15;
    f32x4 acc[8];
    #pragma unroll
    for (int t = 0; t < 8; t++) acc[t] = (f32x4){0.f, 0.f, 0.f, 0.f};
    int arow = rbase + c;
    #pragma unroll
    for (int kk = 0; kk < 16; kk++) {
        int k0 = kk * 32 + g * 8;
        bf16x8 af = {};
        if (arow < n) af = *(const bf16x8*)(t512 + (long)arow * 512 + k0);
        #pragma unroll
        for (int t = 0; t < 8; t++) {
            bf16x8 bf = *(const bf16x8*)(wpj + (long)(t * 16 + c) * 512 + k0);
            acc[t] = MFMA(af, bf, acc[t]);
        }
    }
    #pragma unroll
    for (int t = 0; t < 8; t++) {
        int col = t * 16 + c;
        #pragma unroll
        for (int r = 0; r < 4; r++) {
            int row = rbase + g * 4 + r;
            if (row < n) out[(long)row * D + col] = x_mid[(long)row * D + col] + acc[t][r];
        }
    }
}

extern "C" void kernel_launch(void* const* d_in, const int* in_sizes, int n_in,
                              void* d_out, int out_size, void* d_ws, size_t ws_size,
                              hipStream_t stream) {
    const float* x    = (const float*)d_in[0];
    const int*   eidx = (const int*)d_in[1];
    const float* ea   = (const float*)d_in[2];
    const float* ln1w = (const float*)d_in[3];
    const float* wl   = (const float*)d_in[4];
    const float* bl   = (const float*)d_in[5];
    const float* wr   = (const float*)d_in[6];
    const float* br   = (const float*)d_in[7];
    const float* we   = (const float*)d_in[8];
    const float* att  = (const float*)d_in[9];
    const float* ab   = (const float*)d_in[10];
    const float* ln2w = (const float*)d_in[11];
    const float* wfc  = (const float*)d_in[12];
    const float* wpj  = (const float*)d_in[13];
    int N = in_sizes[0] / D;
    int E = in_sizes[1] / 2;
    const int* srcp = eidx;
    const int* dstp = eidx + E;

    char* ws = (char*)d_ws;
    size_t NB2 = (size_t)N * D * 2;       // bf16 node matrix
    size_t NB4 = (size_t)N * D * 4;       // fp32 node matrix
    size_t E84 = (size_t)E * HEADS * 4;   // num_perm
    size_t o = 0;
    short* xl_bf   = (short*)(ws + o); o += NB2;
    short* xr_bf   = (short*)(ws + o); o += NB2;
    float* numperm = (float*)(ws + o); o += E84;
    float* xmid    = (float*)(ws + o); o += NB4;
    short* hbuf    = (short*)(ws + o); o += NB2;
    short* wbf     = (short*)(ws + o); o += 180224 * 2;
    int* counts    = (int*)(ws + o);   o += (size_t)N * 4;
    int* offsets   = (int*)(ws + o);   o += (size_t)N * 4;
    int* cursor    = (int*)(ws + o);   o += (size_t)N * 4;
    int* posOf     = (int*)(ws + o);   o += (size_t)E * 4;
    int* src_perm  = (int*)(ws + o);   o += (size_t)E * 4;
    int* blocksum  = (int*)(ws + o);   o += 256 * 4;
    short* t512    = (short*)ws;  // overlays xl+xr+numperm after aggregate (N*512*2)

    int nb = (N + 1023) / 1024;

    hipMemsetAsync(counts, 0, (size_t)N * 4, stream);

    convert_weights<<<704, 256, 0, stream>>>(wl, wr, we, wfc, wpj, wbf);
    ln_kernel<<<(N + 3) / 4, 256, 0, stream>>>(x, ln1w, hbuf, N);
    node_lin_kernel<<<(N + 63) / 64, 256, 0, stream>>>(hbuf, wbf, wbf + 16384,
                                                       bl, br, xl_bf, xr_bf, N);
    hist_kernel<<<(E + 255) / 256, 256, 0, stream>>>(dstp, counts, E);
    scan1_kernel<<<nb, 1024, 0, stream>>>(counts, offsets, blocksum, N);
    scan2_kernel<<<1, 256, 0, stream>>>(blocksum, nb);
    scan3_kernel<<<(N + 255) / 256, 256, 0, stream>>>(offsets, blocksum, cursor, N);
    place_kernel<<<(E + 255) / 256, 256, 0, stream>>>(srcp, dstp, cursor, posOf,
                                                      src_perm, E);
    edge_kernel<<<(E + 63) / 64, 256, 0, stream>>>(ea, wbf + 32768, srcp, dstp,
                                                   posOf, xl_bf, xr_bf, att,
                                                   numperm, E);
    aggregate_kernel<<<(N + 3) / 4, 256, 0, stream>>>(src_perm, offsets, counts,
                                                      numperm, xl_bf, x, ab, ln2w,
                                                      xmid, hbuf, N);
    fc_kernel<<<dim3((N + 63) / 64, 2), 256, 0, stream>>>(hbuf, wbf + 49152, t512, N);
    proj_kernel<<<(N + 63) / 64, 256, 0, stream>>>(t512, wbf + 114688, xmid,
                                                   (float*)d_out, N);
}